// Round 3
// baseline (202.846 us; speedup 1.0000x reference)
//
#include <hip/hip_runtime.h>

// Linear attention (non-causal), N=4, L=8192, H=16, D=M=64, fp32.
//   fm(x) = elu(x)+1
//   KV[n,h,d,m] = sum_s fm(K[n,s,h,d]) * V[n,s,h,m]
//   Ksum[n,h,d] = sum_s fm(K[n,s,h,d])
//   z[n,l,h]    = 1/(fm(Q[n,l,h,:]) . Ksum[n,h,:]) + 1e-10
//   out[n,l,h,m]= z * sum_d fm(Q[n,l,h,d]) * KV[n,h,d,m]
//
// R2 post-mortem: pass1 still latency-bound (VALUBusy 34%, occ 25%) — barrier-
// coupled tile loop + 2B/FLOP LDS traffic. R3: wave-independent pass1 — each
// wave owns a 64x64 KV partial in registers (8x8 patch/lane), broadcasts
// k/v octets via __shfl (no LDS, no barriers in main loop), one LDS combine
// at the end. Pass2: fused load issue, one barrier fewer.

#define EPSV      1e-10f
#define L_SEQ     8192
#define NH_TOT    64          // N*H
#define ROWSTRIDE 1024        // H*D floats between consecutive s/l
#define KV_STRIDE 4160        // per-(n,h): 4096 KV + 64 Ksum
#define SLICE     (NH_TOT * KV_STRIDE)   // floats per chunk-slice = 266240
#define QSTRIDE   68

__device__ __forceinline__ float fm(float x) {
    return x > 0.0f ? x + 1.0f : __expf(x);
}

// ---------------- Pass 1: KV + Ksum partial reduction over s ----------------
// grid: (64 nh, CH chunks), block 256 = 4 independent waves.
// Each wave: 64x64 KV partial over rows_per_wave s-rows, 8x8 regs per lane.
// mode=1: store block partial to ws[chunk*NH+nh]; mode=0: atomicAdd to ws[nh].
__global__ __launch_bounds__(256, 4) void kv_reduce_kernel(
    const float* __restrict__ K, const float* __restrict__ V,
    float* __restrict__ ws, int rows_per_wave, int mode)
{
    const int t    = threadIdx.x;
    const int nh   = blockIdx.x;
    const int chunk= blockIdx.y;
    const int n = nh >> 4, h = nh & 15;
    const int wid  = t >> 6;
    const int lane = t & 63;

    // output patch: rows d0..d0+7, cols m0..m0+7
    const int d0 = (lane >> 3) << 3;
    const int m0 = (lane & 7) << 3;
    const int kb = d0 >> 2;              // k-octet source lane base (quad idx)
    const int mb = m0 >> 2;              // v-octet source lane base

    // loader role: row-in-group rp, column quad qd
    const int rp = lane >> 4;
    const int qd = (lane & 15) << 2;

    float acc[8][8] = {};
    float ks0 = 0.f, ks1 = 0.f, ks2 = 0.f, ks3 = 0.f;

    const size_t base  = (size_t)n * (L_SEQ * ROWSTRIDE) + h * 64;
    const int    srow0 = chunk * (rows_per_wave * 4) + wid * rows_per_wave;
    const float* Kp = K + base + (size_t)srow0 * ROWSTRIDE;
    const float* Vp = V + base + (size_t)srow0 * ROWSTRIDE;
    const size_t lofs = (size_t)rp * ROWSTRIDE + qd;

    const int ngroups = rows_per_wave >> 2;

    // prologue: prefetch group 0
    float4 kg = *reinterpret_cast<const float4*>(Kp + lofs);
    float4 vg = *reinterpret_cast<const float4*>(Vp + lofs);

    for (int g = 0; g < ngroups; ++g) {
        // feature-map current K regs + ksum (loader-local, no redundancy)
        float4 kf, vv = vg;
        kf.x = fm(kg.x); kf.y = fm(kg.y); kf.z = fm(kg.z); kf.w = fm(kg.w);
        ks0 += kf.x; ks1 += kf.y; ks2 += kf.z; ks3 += kf.w;

        // issue next group's loads; they fly under the 256-FMA block below
        if (g + 1 < ngroups) {
            const size_t o = (size_t)(g + 1) * (4 * ROWSTRIDE) + lofs;
            kg = *reinterpret_cast<const float4*>(Kp + o);
            vg = *reinterpret_cast<const float4*>(Vp + o);
        }

        // 4 rows: broadcast octets via shfl, rank-1 update 8x8 patch
#pragma unroll
        for (int r = 0; r < 4; ++r) {
            const int sk = (r << 4) + kb;
            const int sv = (r << 4) + mb;
            float ka[8], va[8];
            ka[0] = __shfl(kf.x, sk);     ka[1] = __shfl(kf.y, sk);
            ka[2] = __shfl(kf.z, sk);     ka[3] = __shfl(kf.w, sk);
            ka[4] = __shfl(kf.x, sk + 1); ka[5] = __shfl(kf.y, sk + 1);
            ka[6] = __shfl(kf.z, sk + 1); ka[7] = __shfl(kf.w, sk + 1);
            va[0] = __shfl(vv.x, sv);     va[1] = __shfl(vv.y, sv);
            va[2] = __shfl(vv.z, sv);     va[3] = __shfl(vv.w, sv);
            va[4] = __shfl(vv.x, sv + 1); va[5] = __shfl(vv.y, sv + 1);
            va[6] = __shfl(vv.z, sv + 1); va[7] = __shfl(vv.w, sv + 1);
#pragma unroll
            for (int j = 0; j < 8; ++j)
#pragma unroll
                for (int q = 0; q < 8; ++q)
                    acc[j][q] += ka[j] * va[q];
        }
    }

    // ---- ksum wave-reduce: lanes {l,l+16,l+32,l+48} share quad qd ----
    ks0 += __shfl_xor(ks0, 16); ks0 += __shfl_xor(ks0, 32);
    ks1 += __shfl_xor(ks1, 16); ks1 += __shfl_xor(ks1, 32);
    ks2 += __shfl_xor(ks2, 16); ks2 += __shfl_xor(ks2, 32);
    ks3 += __shfl_xor(ks3, 16); ks3 += __shfl_xor(ks3, 32);

    __shared__ float red[4096];
    __shared__ float ksred[256];
    if (lane < 16) {
        reinterpret_cast<float4*>(ksred)[wid * 16 + lane] =
            make_float4(ks0, ks1, ks2, ks3);
    }

    // ---- sequential cross-wave KV accumulate in LDS ----
    for (int w = 0; w < 4; ++w) {
        if (wid == w) {
#pragma unroll
            for (int j = 0; j < 8; ++j) {
                float* p = &red[(d0 + j) * 64 + m0];
                float4 a0 = make_float4(acc[j][0], acc[j][1], acc[j][2], acc[j][3]);
                float4 a1 = make_float4(acc[j][4], acc[j][5], acc[j][6], acc[j][7]);
                if (w != 0) {
                    float4 b0 = *reinterpret_cast<float4*>(p);
                    float4 b1 = *reinterpret_cast<float4*>(p + 4);
                    a0.x += b0.x; a0.y += b0.y; a0.z += b0.z; a0.w += b0.w;
                    a1.x += b1.x; a1.y += b1.y; a1.z += b1.z; a1.w += b1.w;
                }
                *reinterpret_cast<float4*>(p)     = a0;
                *reinterpret_cast<float4*>(p + 4) = a1;
            }
        }
        __syncthreads();
    }

    // ---- store block partial (coalesced float4) ----
    float* dst = ws + (size_t)(mode ? (chunk * NH_TOT + nh) : nh) * KV_STRIDE;
    if (mode) {
#pragma unroll
        for (int i = 0; i < 4; ++i)
            *reinterpret_cast<float4*>(dst + t * 16 + i * 4) =
                *reinterpret_cast<const float4*>(&red[t * 16 + i * 4]);
        if (t < 64)
            dst[4096 + t] = ksred[t] + ksred[64 + t] + ksred[128 + t] + ksred[192 + t];
    } else {
#pragma unroll
        for (int i = 0; i < 16; ++i)
            atomicAdd(dst + t * 16 + i, red[t * 16 + i]);
        if (t < 64)
            atomicAdd(dst + 4096 + t,
                      ksred[t] + ksred[64 + t] + ksred[128 + t] + ksred[192 + t]);
    }
}

// ---------------- Reduce: sum CH partial slices into slice 0 ----------------
__global__ __launch_bounds__(256) void reduce_kernel(float* __restrict__ ws, int CH)
{
    const int idx = blockIdx.x * 256 + threadIdx.x;
    float s = 0.f;
    for (int c = 0; c < CH; ++c) s += ws[(size_t)c * SLICE + idx];
    ws[idx] = s;
}

// ---------------- Pass 2: out = z * (fm(Q) @ KV) ----------------
// grid: (128 l-chunks of 64 rows, 64 nh), block 256.
__global__ __launch_bounds__(256) void out_kernel(
    const float* __restrict__ Q, const float* __restrict__ KVg,
    float* __restrict__ out)
{
    const int t      = threadIdx.x;
    const int lchunk = blockIdx.x;
    const int nh     = blockIdx.y;
    const int n = nh >> 4, h = nh & 15;

    __shared__ float Ql[64 * QSTRIDE];
    __shared__ float KVl[4096];
    __shared__ float zl[64];

    const float* kvrow = KVg + (size_t)nh * KV_STRIDE;
    const int lane16 = t & 15, grp = t >> 4;
    const int dq = lane16 << 2;
    const size_t qbase = ((size_t)n * L_SEQ + lchunk * 64) * ROWSTRIDE + h * 64;

    // issue everything up front: 4 KV (L2), 4 Q (HBM), 1 Ksum (L1/L2)
    const float4 kv0 = reinterpret_cast<const float4*>(kvrow)[t];
    const float4 kv1 = reinterpret_cast<const float4*>(kvrow)[t + 256];
    const float4 kv2 = reinterpret_cast<const float4*>(kvrow)[t + 512];
    const float4 kv3 = reinterpret_cast<const float4*>(kvrow)[t + 768];
    const float4 qg0 = *reinterpret_cast<const float4*>(Q + qbase + (size_t)(grp)      * ROWSTRIDE + dq);
    const float4 qg1 = *reinterpret_cast<const float4*>(Q + qbase + (size_t)(16 + grp) * ROWSTRIDE + dq);
    const float4 qg2 = *reinterpret_cast<const float4*>(Q + qbase + (size_t)(32 + grp) * ROWSTRIDE + dq);
    const float4 qg3 = *reinterpret_cast<const float4*>(Q + qbase + (size_t)(48 + grp) * ROWSTRIDE + dq);
    const float4 ks4 = *reinterpret_cast<const float4*>(kvrow + 4096 + dq);

    // stage KV
    reinterpret_cast<float4*>(KVl)[t]       = kv0;
    reinterpret_cast<float4*>(KVl)[t + 256] = kv1;
    reinterpret_cast<float4*>(KVl)[t + 512] = kv2;
    reinterpret_cast<float4*>(KVl)[t + 768] = kv3;

    // fm(Q) -> Ql, z per row (16-lane shuffle reduce)
#pragma unroll
    for (int p = 0; p < 4; ++p) {
        const float4 qg = (p == 0) ? qg0 : (p == 1) ? qg1 : (p == 2) ? qg2 : qg3;
        const int rr = p * 16 + grp;
        float4 qf;
        qf.x = fm(qg.x); qf.y = fm(qg.y); qf.z = fm(qg.z); qf.w = fm(qg.w);
        *reinterpret_cast<float4*>(&Ql[rr * QSTRIDE + dq]) = qf;
        float dp = qf.x * ks4.x + qf.y * ks4.y + qf.z * ks4.z + qf.w * ks4.w;
        dp += __shfl_xor(dp, 1);
        dp += __shfl_xor(dp, 2);
        dp += __shfl_xor(dp, 4);
        dp += __shfl_xor(dp, 8);
        if (lane16 == 0) zl[rr] = 1.0f / dp + EPSV;
    }
    __syncthreads();

    // 64x64x64 register-tiled GEMM, 4x4 tile per thread
    const int r0 = grp << 2;
    const int c0 = lane16 << 2;
    float acc[4][4] = {};
#pragma unroll 2
    for (int d = 0; d < 64; d += 4) {
        const float4 b0 = *reinterpret_cast<const float4*>(&KVl[(d + 0) * 64 + c0]);
        const float4 b1 = *reinterpret_cast<const float4*>(&KVl[(d + 1) * 64 + c0]);
        const float4 b2 = *reinterpret_cast<const float4*>(&KVl[(d + 2) * 64 + c0]);
        const float4 b3 = *reinterpret_cast<const float4*>(&KVl[(d + 3) * 64 + c0]);
#define DO_ROW(i) do {                                                              \
        const float4 q = *reinterpret_cast<const float4*>(&Ql[(r0 + (i)) * QSTRIDE + d]); \
        acc[i][0] += q.x * b0.x + q.y * b1.x + q.z * b2.x + q.w * b3.x;             \
        acc[i][1] += q.x * b0.y + q.y * b1.y + q.z * b2.y + q.w * b3.y;             \
        acc[i][2] += q.x * b0.z + q.y * b1.z + q.z * b2.z + q.w * b3.z;             \
        acc[i][3] += q.x * b0.w + q.y * b1.w + q.z * b2.w + q.w * b3.w;             \
    } while (0)
        DO_ROW(0); DO_ROW(1); DO_ROW(2); DO_ROW(3);
#undef DO_ROW
    }

    // epilogue
#pragma unroll
    for (int i = 0; i < 4; ++i) {
        const float z = zl[r0 + i];
        float4 o;
        o.x = acc[i][0] * z; o.y = acc[i][1] * z; o.z = acc[i][2] * z; o.w = acc[i][3] * z;
        *reinterpret_cast<float4*>(out + qbase + (size_t)(r0 + i) * ROWSTRIDE + c0) = o;
    }
}

extern "C" void kernel_launch(void* const* d_in, const int* in_sizes, int n_in,
                              void* d_out, int out_size, void* d_ws, size_t ws_size,
                              hipStream_t stream) {
    const float* Q = (const float*)d_in[0];
    const float* K = (const float*)d_in[1];
    const float* V = (const float*)d_in[2];
    float* out = (float*)d_out;
    float* ws  = (float*)d_ws;

    const size_t per_slice = (size_t)SLICE * sizeof(float);   // ~1.06 MB
    size_t max_ch = ws_size / per_slice;
    int CH = max_ch >= 16 ? 16 : (max_ch >= 8 ? 8 : 0);

    if (CH > 0) {
        const int rows_per_wave = L_SEQ / (CH * 4);
        kv_reduce_kernel<<<dim3(NH_TOT, CH), 256, 0, stream>>>(K, V, ws, rows_per_wave, 1);
        reduce_kernel<<<SLICE / 256, 256, 0, stream>>>(ws, CH);
    } else {
        hipMemsetAsync(d_ws, 0, per_slice, stream);
        kv_reduce_kernel<<<dim3(NH_TOT, 16), 256, 0, stream>>>(K, V, ws, L_SEQ / 64, 0);
    }
    out_kernel<<<dim3(L_SEQ / 64, NH_TOT), 256, 0, stream>>>(Q, ws, out);
}